// Round 3
// baseline (512.502 us; speedup 1.0000x reference)
//
#include <hip/hip_runtime.h>

// MultisenseLearner: out[b] = logsumexp_{s,t}( sum_d W[j,d,s]*V[i,d,t] + wb[j,s] + vb[i,t] )
// V,W: (50000,300,4) f32; vb,wb: (50000,4) f32; IJ: (100000,2) int; out: (100000,) f32.
//
// R5: cross-element software pipeline (T14 async-STAGE). R3/R4 proved that
// within-element reordering can't move the 193us / 2.5TB/s plateau: no pipe is
// saturated, so each wave is a serial latency chain (ij -> addr -> loads ->
// FMA -> 21-deep shuffle chain -> exp/log). Now each wave processes ~24
// elements grid-stride, double-buffered in REGISTERS via inline-asm loads:
// while computing element e it has element e+1's 10KB already in flight.
// Counted vmcnt (never 0 in steady state) + sched_barrier(0) per rule #18.
// Queue per step: [ij(e+1):2][stage(e):10][bias(e):2] (+1 out-store) ->
// wait vmcnt(12) -> issue 14 for e+1 -> wait vmcnt(14) -> compute e.
// NOTE: if this ever misverifies, check for scratch spills (a spill of an
// in-flight asm dest reg would be garbage) -- VGPR budget ~140 is safe.

typedef __attribute__((ext_vector_type(4))) float f32x4;

constexpr int D    = 300;
constexpr int NS   = 4;
constexpr int ROWB = D * NS * 4;   // 4800 bytes per row

#define S_VMCNT(N) asm volatile("s_waitcnt vmcnt(" #N ")" ::: "memory")

#define STAGE(NV, NW, pV_, pW_, pVt_, pWt_)                                                  \
    asm volatile("global_load_dwordx4 %0, %1, off"             : "=v"(NV[0]) : "v"(pV_));    \
    asm volatile("global_load_dwordx4 %0, %1, off offset:1024" : "=v"(NV[1]) : "v"(pV_));    \
    asm volatile("global_load_dwordx4 %0, %1, off offset:2048" : "=v"(NV[2]) : "v"(pV_));    \
    asm volatile("global_load_dwordx4 %0, %1, off offset:3072" : "=v"(NV[3]) : "v"(pV_));    \
    asm volatile("global_load_dwordx4 %0, %1, off"             : "=v"(NV[4]) : "v"(pVt_));   \
    asm volatile("global_load_dwordx4 %0, %1, off"             : "=v"(NW[0]) : "v"(pW_));    \
    asm volatile("global_load_dwordx4 %0, %1, off offset:1024" : "=v"(NW[1]) : "v"(pW_));    \
    asm volatile("global_load_dwordx4 %0, %1, off offset:2048" : "=v"(NW[2]) : "v"(pW_));    \
    asm volatile("global_load_dwordx4 %0, %1, off offset:3072" : "=v"(NW[3]) : "v"(pW_));    \
    asm volatile("global_load_dwordx4 %0, %1, off"             : "=v"(NW[4]) : "v"(pWt_));

// Compute element e from CUR buffers + biases, store out[e]. Uses outer
// lane/mT/b5..b2/s-t classes. Identical math to the verified R2 kernel.
#define COMPUTE(CV, CW, WBC, VBC)                                                            \
  {                                                                                          \
    float acc[16];                                                                           \
    { const float v0=CV[0].x, v1=CV[0].y, v2=CV[0].z, v3=CV[0].w;                            \
      const float w0=CW[0].x, w1=CW[0].y, w2=CW[0].z, w3=CW[0].w;                            \
      acc[ 0]=w0*v0; acc[ 1]=w0*v1; acc[ 2]=w0*v2; acc[ 3]=w0*v3;                            \
      acc[ 4]=w1*v0; acc[ 5]=w1*v1; acc[ 6]=w1*v2; acc[ 7]=w1*v3;                            \
      acc[ 8]=w2*v0; acc[ 9]=w2*v1; acc[10]=w2*v2; acc[11]=w2*v3;                            \
      acc[12]=w3*v0; acc[13]=w3*v1; acc[14]=w3*v2; acc[15]=w3*v3; }                          \
    _Pragma("unroll")                                                                        \
    for (int k = 1; k < 5; ++k) {                                                            \
      f32x4 vv = CV[k]; f32x4 ww = CW[k];                                                    \
      if (k == 4) { ww.x*=mT; ww.y*=mT; ww.z*=mT; ww.w*=mT; }                                \
      const float v0=vv.x, v1=vv.y, v2=vv.z, v3=vv.w;                                        \
      const float w0=ww.x, w1=ww.y, w2=ww.z, w3=ww.w;                                        \
      acc[ 0]=fmaf(w0,v0,acc[ 0]); acc[ 1]=fmaf(w0,v1,acc[ 1]);                              \
      acc[ 2]=fmaf(w0,v2,acc[ 2]); acc[ 3]=fmaf(w0,v3,acc[ 3]);                              \
      acc[ 4]=fmaf(w1,v0,acc[ 4]); acc[ 5]=fmaf(w1,v1,acc[ 5]);                              \
      acc[ 6]=fmaf(w1,v2,acc[ 6]); acc[ 7]=fmaf(w1,v3,acc[ 7]);                              \
      acc[ 8]=fmaf(w2,v0,acc[ 8]); acc[ 9]=fmaf(w2,v1,acc[ 9]);                              \
      acc[10]=fmaf(w2,v2,acc[10]); acc[11]=fmaf(w2,v3,acc[11]);                              \
      acc[12]=fmaf(w3,v0,acc[12]); acc[13]=fmaf(w3,v1,acc[13]);                              \
      acc[14]=fmaf(w3,v2,acc[14]); acc[15]=fmaf(w3,v3,acc[15]); }                            \
    float r8[8];                                                                             \
    _Pragma("unroll")                                                                        \
    for (int mm = 0; mm < 8; ++mm) {                                                         \
      const float send = b5 ? acc[mm]     : acc[mm + 8];                                     \
      const float keep = b5 ? acc[mm + 8] : acc[mm];                                         \
      r8[mm] = keep + __shfl_xor(send, 32, 64); }                                            \
    float r4[4];                                                                             \
    _Pragma("unroll")                                                                        \
    for (int mm = 0; mm < 4; ++mm) {                                                         \
      const float send = b4_ ? r8[mm]     : r8[mm + 4];                                      \
      const float keep = b4_ ? r8[mm + 4] : r8[mm];                                          \
      r4[mm] = keep + __shfl_xor(send, 16, 64); }                                            \
    float r2[2];                                                                             \
    _Pragma("unroll")                                                                        \
    for (int mm = 0; mm < 2; ++mm) {                                                         \
      const float send = b3 ? r4[mm]     : r4[mm + 2];                                       \
      const float keep = b3 ? r4[mm + 2] : r4[mm];                                           \
      r2[mm] = keep + __shfl_xor(send, 8, 64); }                                             \
    float r1;                                                                                \
    { const float send = b2 ? r2[0] : r2[1];                                                 \
      const float keep = b2 ? r2[1] : r2[0];                                                 \
      r1 = keep + __shfl_xor(send, 4, 64); }                                                 \
    r1 += __shfl_xor(r1, 2, 64);                                                             \
    r1 += __shfl_xor(r1, 1, 64);                                                             \
    float ex = expf(r1 + (WBC) + (VBC));                                                     \
    ex += __shfl_xor(ex,  4, 64);                                                            \
    ex += __shfl_xor(ex,  8, 64);                                                            \
    ex += __shfl_xor(ex, 16, 64);                                                            \
    ex += __shfl_xor(ex, 32, 64);                                                            \
    if (lane == 0) out[e] = logf(ex);                                                        \
  }

// One pipeline step: consume ij(eNext) [IJI/IJJ], issue ij(eNN)->IJI2/IJJ2,
// stage eNext -> NV/NW (+biases WBN/VBN), then compute e from CV/CW.
#define STEP(CV, CW, WBC, VBC, IJI, IJJ, NV, NW, WBN, VBN, IJI2, IJJ2)                       \
  {                                                                                          \
    S_VMCNT(12); __builtin_amdgcn_sched_barrier(0);                                          \
    const int iN = (int)(IJI), jN = (int)(IJJ);                                              \
    const int eNN = (eNext + stride < B) ? (eNext + stride) : (B - 1);                       \
    { const char* pI_ = ijb + (size_t)eNN * ijstride;                                        \
      asm volatile("global_load_dword %0, %1, off" : "=v"(IJI2) : "v"(pI_));                 \
      asm volatile("global_load_dword %0, %1, off" : "=v"(IJJ2) : "v"(pI_ + ijoff)); }       \
    { const char* pV_  = (const char*)V + (size_t)iN * ROWB + laneB;                         \
      const char* pW_  = (const char*)W + (size_t)jN * ROWB + laneB;                         \
      const char* pVt_ = (const char*)V + (size_t)iN * ROWB + dcb;                           \
      const char* pWt_ = (const char*)W + (size_t)jN * ROWB + dcb;                           \
      STAGE(NV, NW, pV_, pW_, pVt_, pWt_);                                                   \
      const char* pwb_ = (const char*)wb + (size_t)jN * 16 + s4;                             \
      const char* pvb_ = (const char*)vb + (size_t)iN * 16 + t4;                             \
      asm volatile("global_load_dword %0, %1, off" : "=v"(WBN) : "v"(pwb_));                 \
      asm volatile("global_load_dword %0, %1, off" : "=v"(VBN) : "v"(pvb_)); }               \
    S_VMCNT(14); __builtin_amdgcn_sched_barrier(0);                                          \
    COMPUTE(CV, CW, WBC, VBC);                                                               \
    e = eNext; eNext = eNN;                                                                  \
  }

__global__ __launch_bounds__(256) void multisense_kernel(
    const float* __restrict__ V,
    const float* __restrict__ W,
    const float* __restrict__ vb,
    const float* __restrict__ wb,
    const unsigned int* __restrict__ IJw,   // raw 32-bit view of IJ
    float* __restrict__ out,
    int B,
    int mode,                               // 1 = int64 data, 2 = int32 data, 0 = probe on device
    int stride)                             // total wave count (grid-stride)
{
    const int lane = threadIdx.x & 63;
    const int wid  = blockIdx.x * (blockDim.x >> 6) + (threadIdx.x >> 6);
    int e = wid;
    if (e >= B) return;

    // --- ij addressing (bytes) ---
    size_t ijstride, ijoff;
    if (mode == 1)      { ijstride = 16; ijoff = 8; }
    else if (mode == 2) { ijstride = 8;  ijoff = 4; }
    else {
        unsigned int probe = (lane < 32) ? IJw[2 * lane + 1] : 0u;
        const bool isI64 = (__ballot(probe != 0u) == 0ull);
        ijstride = isI64 ? 16 : 8;  ijoff = isI64 ? 8 : 4;
    }
    const char* ijb = (const char*)IJw;

    // --- loop-invariant lane geometry ---
    const int    s_idx = (lane >> 4) & 3;
    const int    t_idx = (lane >> 2) & 3;
    const size_t s4    = (size_t)s_idx * 4;
    const size_t t4    = (size_t)t_idx * 4;
    const int    laneB = lane * 16;
    const int    d4    = 256 + lane;                       // tail chunk d index
    const size_t dcb   = (size_t)((d4 < D) ? d4 : 0) * 16; // clamped tail byte off
    const float  mT    = (d4 < D) ? 1.0f : 0.0f;           // tail mask
    const bool   b5  = (lane & 32) != 0;
    const bool   b4_ = (lane & 16) != 0;
    const bool   b3  = (lane & 8)  != 0;
    const bool   b2  = (lane & 4)  != 0;

    const int n = 1 + (B - 1 - e) / stride;   // elements this wave computes

    // --- double-buffered state (asm loads write these directly) ---
    f32x4 vA[5], wA[5], vB_[5], wB_[5];
    float wbA, vbA, wbB, vbB;
    unsigned int ijiA, ijjA, ijiB, ijjB;

    // --- prologue: stage e -> A buffers; ij(eNext) in flight in B pair ---
    { const char* pI = ijb + (size_t)e * ijstride;
      asm volatile("global_load_dword %0, %1, off" : "=v"(ijiB) : "v"(pI));
      asm volatile("global_load_dword %0, %1, off" : "=v"(ijjB) : "v"(pI + ijoff)); }
    S_VMCNT(0); __builtin_amdgcn_sched_barrier(0);
    int eNext = (e + stride < B) ? (e + stride) : (B - 1);
    {
        const int i0 = (int)ijiB, j0 = (int)ijjB;
        // issue ij(eNext) FIRST so it is oldest in the queue (old pair values
        // already consumed into i0/j0 -> safe to reuse the same registers)
        const char* pI = ijb + (size_t)eNext * ijstride;
        asm volatile("global_load_dword %0, %1, off" : "=v"(ijiB) : "v"(pI));
        asm volatile("global_load_dword %0, %1, off" : "=v"(ijjB) : "v"(pI + ijoff));
        const char* pV  = (const char*)V + (size_t)i0 * ROWB + laneB;
        const char* pW  = (const char*)W + (size_t)j0 * ROWB + laneB;
        const char* pVt = (const char*)V + (size_t)i0 * ROWB + dcb;
        const char* pWt = (const char*)W + (size_t)j0 * ROWB + dcb;
        STAGE(vA, wA, pV, pW, pVt, pWt);
        const char* pwb = (const char*)wb + (size_t)j0 * 16 + s4;
        const char* pvb = (const char*)vb + (size_t)i0 * 16 + t4;
        asm volatile("global_load_dword %0, %1, off" : "=v"(wbA) : "v"(pwb));
        asm volatile("global_load_dword %0, %1, off" : "=v"(vbA) : "v"(pvb));
    }
    // queue now (oldest->newest): ij(eNext):2, stage(e):10, bias(e):2  == 14

    int rem = n;
    for (;;) {
        STEP(vA,  wA,  wbA, vbA, ijiB, ijjB, vB_, wB_, wbB, vbB, ijiA, ijjA);
        if (--rem == 0) break;
        STEP(vB_, wB_, wbB, vbB, ijiA, ijjA, vA,  wA,  wbA, vbA, ijiB, ijjB);
        if (--rem == 0) break;
    }
}

extern "C" void kernel_launch(void* const* d_in, const int* in_sizes, int n_in,
                              void* d_out, int out_size, void* d_ws, size_t ws_size,
                              hipStream_t stream) {
    const float* V  = (const float*)d_in[0];
    const float* W  = (const float*)d_in[1];
    const float* vb = (const float*)d_in[2];
    const float* wb = (const float*)d_in[3];
    const unsigned int* IJ = (const unsigned int*)d_in[4];
    float* out = (float*)d_out;

    const int B = out_size;                  // one output per batch element

    // Resolve IJ element width on the host if in_sizes is in bytes:
    // int64 -> B*2*8 bytes, int32 -> B*2*4 bytes. Else device probe (mode 0).
    int mode = 0;
    const long long szIJ = (long long)in_sizes[4];
    if      (szIJ == (long long)B * 16) mode = 1;
    else if (szIJ == (long long)B * 8)  mode = 2;

    const int wavesPerBlock = 4;             // 256 threads
    int blocks = 1024;                       // ~4096 waves, ~24 elements each
    const int maxBlocks = (B + wavesPerBlock - 1) / wavesPerBlock;
    if (blocks > maxBlocks) blocks = maxBlocks;
    const int stride = blocks * wavesPerBlock;

    dim3 block(256);
    dim3 grid(blocks);
    hipLaunchKernelGGL(multisense_kernel, grid, block, 0, stream,
                       V, W, vb, wb, IJ, out, B, mode, stride);
}